// Round 1
// baseline (831.614 us; speedup 1.0000x reference)
//
#include <hip/hip_runtime.h>
#include <math.h>

#define SS 512
#define BB 256
#define DIN 202
#define HH 100
#define TT 19

__device__ __forceinline__ float rl(float v, int i) {
    return __int_as_float(__builtin_amdgcn_readlane(__float_as_int(v), i));
}
__device__ __forceinline__ float rfl(float v) {
    return __int_as_float(__builtin_amdgcn_readfirstlane(__float_as_int(v)));
}

// ---------------------------------------------------------------------------
// K1: input projection, both directions.
// xp[(s*BB+b)*200 + dir*100 + c] = sum_k x[s,b,k]*W[c,k] + bih[c] + bhh[c]
// Tile: 128 rows x 128 cols (100 used) x K16. 256 thr, 8x8 acc/thread.
// ---------------------------------------------------------------------------
__global__ __launch_bounds__(256) void k_inproj(
    const float* __restrict__ x, const float* __restrict__ Wf, const float* __restrict__ Wb,
    const float* __restrict__ bihf, const float* __restrict__ bhhf,
    const float* __restrict__ bihb, const float* __restrict__ bhhb,
    float* __restrict__ xp) {
  const int dir = blockIdx.y;
  const float* W = dir ? Wb : Wf;
  const float* bih = dir ? bihb : bihf;
  const float* bhh = dir ? bhhb : bhhf;
  const int m0 = blockIdx.x * 128;
  __shared__ float xs[16][128];
  __shared__ float ws[16][128];
  const int t = threadIdx.x;
  const int tr = t & 15, tc = t >> 4;
  float acc[8][8];
  #pragma unroll
  for (int i = 0; i < 8; ++i)
    #pragma unroll
    for (int j = 0; j < 8; ++j) acc[i][j] = 0.f;

  for (int k0 = 0; k0 < DIN; k0 += 16) {
    #pragma unroll
    for (int i = 0; i < 8; ++i) {
      int idx = t + 256 * i;
      int r = idx >> 4, kk = idx & 15;
      int gk = k0 + kk;
      xs[kk][r] = (gk < DIN) ? x[(size_t)(m0 + r) * DIN + gk] : 0.f;
      ws[kk][r] = (r < HH && gk < DIN) ? W[r * DIN + gk] : 0.f;
    }
    __syncthreads();
    #pragma unroll
    for (int kk = 0; kk < 16; ++kk) {
      float4 a0 = *(const float4*)&xs[kk][tr * 8];
      float4 a1 = *(const float4*)&xs[kk][tr * 8 + 4];
      float4 b0 = *(const float4*)&ws[kk][tc * 8];
      float4 b1 = *(const float4*)&ws[kk][tc * 8 + 4];
      float a[8] = {a0.x, a0.y, a0.z, a0.w, a1.x, a1.y, a1.z, a1.w};
      float bv[8] = {b0.x, b0.y, b0.z, b0.w, b1.x, b1.y, b1.z, b1.w};
      #pragma unroll
      for (int ii = 0; ii < 8; ++ii)
        #pragma unroll
        for (int jj = 0; jj < 8; ++jj)
          acc[ii][jj] = fmaf(a[ii], bv[jj], acc[ii][jj]);
    }
    __syncthreads();
  }
  float biasv[8];
  #pragma unroll
  for (int jj = 0; jj < 8; ++jj) {
    int c = tc * 8 + jj;
    biasv[jj] = (c < HH) ? (bih[c] + bhh[c]) : 0.f;
  }
  #pragma unroll
  for (int ii = 0; ii < 8; ++ii) {
    int r = m0 + tr * 8 + ii;
    size_t rowbase = (size_t)r * 200 + dir * 100;
    #pragma unroll
    for (int j4 = 0; j4 < 2; ++j4) {
      int c = tc * 8 + j4 * 4;
      if (c + 3 < HH) {
        float4 v;
        v.x = acc[ii][j4 * 4 + 0] + biasv[j4 * 4 + 0];
        v.y = acc[ii][j4 * 4 + 1] + biasv[j4 * 4 + 1];
        v.z = acc[ii][j4 * 4 + 2] + biasv[j4 * 4 + 2];
        v.w = acc[ii][j4 * 4 + 3] + biasv[j4 * 4 + 3];
        *(float4*)&xp[rowbase + c] = v;
      } else {
        #pragma unroll
        for (int e = 0; e < 4; ++e) {
          int cc = c + e;
          if (cc < HH) xp[rowbase + cc] = acc[ii][j4 * 4 + e] + biasv[j4 * 4 + e];
        }
      }
    }
  }
}

// ---------------------------------------------------------------------------
// K2: RNN scan, one (batch, dir) chain per workgroup. 320 threads:
//  t in [0,200): recurrence, 2 threads/output (k-split 52/48, padded to 52)
//  t in [256,294): tag-logit partials of previous step's h (wave 4)
// h ping-pong in LDS; xp prefetched 2 steps ahead; partial logits to plog.
// ---------------------------------------------------------------------------
__global__ __launch_bounds__(320) void k_rnn(
    const float* __restrict__ xp, const float* __restrict__ Whf, const float* __restrict__ Whb,
    const float* __restrict__ Wtag, float* __restrict__ plogf, float* __restrict__ plogb) {
  const int b = blockIdx.x;
  const int dir = blockIdx.y;
  const float* Whh = dir ? Whb : Whf;
  float* plog = dir ? plogb : plogf;
  __shared__ float hbuf[2][104];
  const int t = threadIdx.x;
  const bool isrec = (t < 200);
  const bool islog = (t >= 256 && t < 256 + 2 * TT);
  const int half = t & 1;
  const int kbase = half * 52;
  const int j = t >> 1;
  const int tg = (t - 256) >> 1;
  float4 Wreg[13];
  if (isrec) {
    #pragma unroll
    for (int q = 0; q < 13; ++q) {
      float tmp[4];
      #pragma unroll
      for (int e = 0; e < 4; ++e) {
        int k = kbase + 4 * q + e;
        tmp[e] = (k < HH) ? Whh[j * HH + k] : 0.f;
      }
      Wreg[q] = make_float4(tmp[0], tmp[1], tmp[2], tmp[3]);
    }
  } else if (islog) {
    #pragma unroll
    for (int q = 0; q < 13; ++q) {
      float tmp[4];
      #pragma unroll
      for (int e = 0; e < 4; ++e) {
        int k = kbase + 4 * q + e;
        tmp[e] = (k < HH) ? Wtag[tg * (2 * HH) + dir * HH + k] : 0.f;
      }
      Wreg[q] = make_float4(tmp[0], tmp[1], tmp[2], tmp[3]);
    }
  } else {
    #pragma unroll
    for (int q = 0; q < 13; ++q) Wreg[q] = make_float4(0.f, 0.f, 0.f, 0.f);
  }
  if (t < 104) { hbuf[0][t] = 0.f; hbuf[1][t] = 0.f; }
  __syncthreads();

  const int colbase = dir * HH;
  float xv0 = 0.f, xv1 = 0.f;
  if (isrec && half == 0) {
    int sx0 = dir ? (SS - 1) : 0;
    int sx1 = dir ? (SS - 2) : 1;
    xv0 = xp[((size_t)sx0 * BB + b) * 200 + colbase + j];
    xv1 = xp[((size_t)sx1 * BB + b) * 200 + colbase + j];
  }
  int p = 0;
  for (int s = 0; s < SS; ++s) {
    float xv2 = 0.f;
    if (isrec && half == 0 && s + 2 < SS) {
      int sx2 = dir ? (SS - 3 - s) : (s + 2);
      xv2 = xp[((size_t)sx2 * BB + b) * 200 + colbase + j];
    }
    float acc = 0.f;
    const bool work = isrec || (islog && s > 0);
    if (work) {
      const float* hp = hbuf[p];
      #pragma unroll
      for (int q = 0; q < 13; ++q) {
        float4 h4 = *(const float4*)&hp[kbase + 4 * q];
        acc = fmaf(Wreg[q].x, h4.x, acc);
        acc = fmaf(Wreg[q].y, h4.y, acc);
        acc = fmaf(Wreg[q].z, h4.z, acc);
        acc = fmaf(Wreg[q].w, h4.w, acc);
      }
      acc += __shfl_xor(acc, 1);
    }
    float hnew = 0.f;
    if (isrec && half == 0) {
      float z = xv0 + acc;
      float e = __expf(-2.f * fabsf(z));
      float th = __fdividef(1.f - e, 1.f + e);
      hnew = copysignf(th, z);
    }
    if (islog && s > 0 && half == 0) {
      int sxp = dir ? (SS - s) : (s - 1);  // seq index of h_{s-1}
      plog[((size_t)sxp * BB + b) * TT + tg] = acc;
    }
    if (isrec && half == 0) hbuf[1 - p][j] = hnew;
    __syncthreads();
    p ^= 1;
    xv0 = xv1; xv1 = xv2;
  }
  // logits of the final h (in hbuf[p])
  if (islog) {
    float acc = 0.f;
    const float* hp = hbuf[p];
    #pragma unroll
    for (int q = 0; q < 13; ++q) {
      float4 h4 = *(const float4*)&hp[kbase + 4 * q];
      acc = fmaf(Wreg[q].x, h4.x, acc);
      acc = fmaf(Wreg[q].y, h4.y, acc);
      acc = fmaf(Wreg[q].z, h4.z, acc);
      acc = fmaf(Wreg[q].w, h4.w, acc);
    }
    acc += __shfl_xor(acc, 1);
    if (half == 0) {
      int sxp = dir ? 0 : (SS - 1);
      plog[((size_t)sxp * BB + b) * TT + tg] = acc;
    }
  }
}

// ---------------------------------------------------------------------------
// K3: logits = plogf + plogb + b_tag; probs = softmax over 19 tags.
// LDS-staged for coalesced global loads/stores. 256 rows per block.
// ---------------------------------------------------------------------------
__global__ __launch_bounds__(256) void k_softmax(
    const float* __restrict__ plogf, const float* __restrict__ plogb,
    const float* __restrict__ btag, float* __restrict__ probs) {
  __shared__ float ls[BB * TT];  // 4864 floats
  const size_t base = (size_t)blockIdx.x * (BB * TT);
  const int t = threadIdx.x;
  #pragma unroll
  for (int i = 0; i < TT; ++i) {
    int idx = t + 256 * i;
    ls[idx] = plogf[base + idx] + plogb[base + idx] + btag[idx % TT];
  }
  __syncthreads();
  float v[TT];
  float m = -1e30f;
  #pragma unroll
  for (int i = 0; i < TT; ++i) { v[i] = ls[t * TT + i]; m = fmaxf(m, v[i]); }
  float ssum = 0.f;
  #pragma unroll
  for (int i = 0; i < TT; ++i) { v[i] = __expf(v[i] - m); ssum += v[i]; }
  float inv = __fdividef(1.f, ssum);
  #pragma unroll
  for (int i = 0; i < TT; ++i) ls[t * TT + i] = v[i] * inv;
  __syncthreads();
  #pragma unroll
  for (int i = 0; i < TT; ++i) {
    int idx = t + 256 * i;
    probs[base + idx] = ls[idx];
  }
}

// ---------------------------------------------------------------------------
// K4: CRF sum log-likelihood. One wave per sequence (n = s index, L = BB).
// Forward algo: alpha_new[j] = em[l,j] + m + log(sum_i exp(alpha_i-m)*E[i,j]),
// E = exp(trans) in registers (column per lane), m = readfirstlane(alpha)
// (tag-spread < 2, provably safe). Emissions chunk-staged in LDS.
// ---------------------------------------------------------------------------
__global__ __launch_bounds__(256) void k_crf(
    const float* __restrict__ probs, const int* __restrict__ y,
    const float* __restrict__ start, const float* __restrict__ endt,
    const float* __restrict__ trans, float* __restrict__ out) {
  __shared__ float ltr[TT * TT];
  __shared__ float lem[4][64 * TT];
  const int t = threadIdx.x;
  const int wave = t >> 6, lane = t & 63;
  const int n = blockIdx.x * 4 + wave;
  for (int i = t; i < TT * TT; i += 256) ltr[i] = trans[i];
  __syncthreads();
  const float* em = probs + (size_t)n * BB * TT;
  const int* yn = y + n * BB;
  float Ereg[TT];
  #pragma unroll
  for (int i = 0; i < TT; ++i) Ereg[i] = (lane < TT) ? __expf(ltr[i * TT + lane]) : 0.f;
  float num = 0.f;
  float alpha = -1e30f;
  for (int c = 0; c < 4; ++c) {
    __syncthreads();
    for (int i = lane; i < 64 * TT; i += 64) lem[wave][i] = em[c * (64 * TT) + i];
    __syncthreads();
    {  // numerator piece: l = c*64 + lane
      int l = c * 64 + lane;
      int yt = yn[l];
      num += lem[wave][lane * TT + yt];
      if (l < BB - 1) num += ltr[yt * TT + yn[l + 1]];
    }
    int llstart = 0;
    if (c == 0) {
      alpha = (lane < TT) ? (start[lane] + lem[wave][lane]) : -1e30f;
      llstart = 1;
    }
    for (int ll = llstart; ll < 64; ++ll) {
      float m = rfl(alpha);
      float ea = __expf(alpha - m);
      float s0 = 0.f, s1 = 0.f;
      #pragma unroll
      for (int i = 0; i < TT; i += 2) {
        s0 = fmaf(rl(ea, i), Ereg[i], s0);
        if (i + 1 < TT) s1 = fmaf(rl(ea, i + 1), Ereg[i + 1], s1);
      }
      float ssum = s0 + s1;
      float em_l = (lane < TT) ? lem[wave][ll * TT + lane] : 0.f;
      alpha = em_l + m + __logf(ssum);
    }
  }
  #pragma unroll
  for (int o = 1; o < 64; o <<= 1) num += __shfl_xor(num, o);
  float av = alpha + ((lane < TT) ? endt[lane] : 0.f);
  float m2 = rfl(av);
  float ex = (lane < TT) ? __expf(av - m2) : 0.f;
  #pragma unroll
  for (int o = 1; o < 64; o <<= 1) ex += __shfl_xor(ex, o);
  if (lane == 0) {
    float denom = m2 + __logf(ex);
    float res = (start[yn[0]] + endt[yn[BB - 1]] + num) - denom;
    atomicAdd(out, res);
  }
}

// ---------------------------------------------------------------------------
extern "C" void kernel_launch(void* const* d_in, const int* in_sizes, int n_in,
                              void* d_out, int out_size, void* d_ws, size_t ws_size,
                              hipStream_t stream) {
  const float* x     = (const float*)d_in[0];
  const int*   y     = (const int*)d_in[1];
  const float* Wihf  = (const float*)d_in[2];
  const float* Whhf  = (const float*)d_in[3];
  const float* bihf  = (const float*)d_in[4];
  const float* bhhf  = (const float*)d_in[5];
  const float* Wihb  = (const float*)d_in[6];
  const float* Whhb  = (const float*)d_in[7];
  const float* bihb  = (const float*)d_in[8];
  const float* bhhb  = (const float*)d_in[9];
  const float* Wtag  = (const float*)d_in[10];
  const float* btag  = (const float*)d_in[11];
  const float* stt   = (const float*)d_in[12];
  const float* endt  = (const float*)d_in[13];
  const float* trans = (const float*)d_in[14];

  float* ws    = (float*)d_ws;
  float* xp    = ws;                                    // 131072*200 floats
  float* plogf = xp    + (size_t)131072 * 200;          // 131072*19
  float* plogb = plogf + (size_t)131072 * TT;           // 131072*19
  float* probs = plogb + (size_t)131072 * TT;           // 131072*19

  hipMemsetAsync(d_out, 0, sizeof(float) * out_size, stream);

  k_inproj<<<dim3(1024, 2), 256, 0, stream>>>(x, Wihf, Wihb, bihf, bhhf, bihb, bhhb, xp);
  k_rnn<<<dim3(256, 2), 320, 0, stream>>>(xp, Whhf, Whhb, Wtag, plogf, plogb);
  k_softmax<<<512, 256, 0, stream>>>(plogf, plogb, btag, probs);
  k_crf<<<128, 256, 0, stream>>>(probs, y, stt, endt, trans, (float*)d_out);
}

// Round 2
// 573.332 us; speedup vs baseline: 1.4505x; 1.4505x over previous
//
#include <hip/hip_runtime.h>
#include <math.h>

#define SS 512
#define BB 256
#define DIN 202
#define HH 100
#define TT 19

typedef short short8 __attribute__((ext_vector_type(8)));
typedef float f32x4 __attribute__((ext_vector_type(4)));

__device__ __forceinline__ float rl(float v, int i) {
    return __int_as_float(__builtin_amdgcn_readlane(__float_as_int(v), i));
}
__device__ __forceinline__ float rfl(float v) {
    return __int_as_float(__builtin_amdgcn_readfirstlane(__float_as_int(v)));
}
__device__ __forceinline__ short f2bf(float f) {
  unsigned u = __float_as_uint(f);
  u += 0x7fff + ((u >> 16) & 1);   // RNE; inputs are well-behaved (no NaN/Inf)
  return (short)(u >> 16);
}

// ---------------------------------------------------------------------------
// K1: input projection via bf16 MFMA. One GEMM:
//   C[131072 x 200] = X[131072 x 202] . W^T,  W = [Wf; Wb] (200 x 202)
// xp row layout [f:100 | b:100] == concatenated W rows, so dirs fuse for free.
// Block: 256 thr / 4 waves, M-tile 128, N padded to 208 (13 n-frags), K
// chunks of 32. LDS tiles stored FRAGMENT-LINEAR (lane l owns bytes
// [tile*1024 + l*16)) so ds_write_b128 / ds_read_b128 are conflict-free —
// R0's 6.47e7 SQ_LDS_BANK_CONFLICT came from the strided float4 reads.
// ---------------------------------------------------------------------------
__global__ __launch_bounds__(256) void k_inproj(
    const float* __restrict__ x,
    const float* __restrict__ Wf, const float* __restrict__ Wb,
    const float* __restrict__ bihf, const float* __restrict__ bhhf,
    const float* __restrict__ bihb, const float* __restrict__ bhhb,
    float* __restrict__ xp) {
  __shared__ short lA[8 * 512];    // 8 m-frag tiles, frag-linear (8 KB)
  __shared__ short lB[13 * 512];   // 13 n-frag tiles (13 KB)
  __shared__ float lbias[208];
  const int t = threadIdx.x;
  const int m0 = blockIdx.x * 128;
  const int wv = t >> 6, lane = t & 63;
  const int li = lane & 15;

  if (t < 208) {
    float bv = 0.f;
    if (t < 100) bv = bihf[t] + bhhf[t];
    else if (t < 200) bv = bihb[t - 100] + bhhb[t - 100];
    lbias[t] = bv;
  }

  f32x4 acc[2][13];
  #pragma unroll
  for (int mf = 0; mf < 2; ++mf)
    #pragma unroll
    for (int nf = 0; nf < 13; ++nf)
      acc[mf][nf] = (f32x4){0.f, 0.f, 0.f, 0.f};

  for (int kc = 0; kc < 7; ++kc) {
    const int k0 = kc * 32;
    __syncthreads();  // previous compute done before LDS overwrite
    // ---- stage A: 8 frag-tiles x 64 lane-units = 512 units ----
    #pragma unroll
    for (int r = 0; r < 2; ++r) {
      int u = t + 256 * r;
      int ft = u >> 6, ul = u & 63;
      int i = ul & 15, kq = ul >> 4;
      int kbase = k0 + kq * 8;
      const float* src = x + (size_t)(m0 + ft * 16 + i) * DIN + kbase;
      union { short s[8]; int4 v; } pk;
      if (kbase + 7 < DIN) {
        float2 v0 = *(const float2*)(src);
        float2 v1 = *(const float2*)(src + 2);
        float2 v2 = *(const float2*)(src + 4);
        float2 v3 = *(const float2*)(src + 6);
        pk.s[0] = f2bf(v0.x); pk.s[1] = f2bf(v0.y);
        pk.s[2] = f2bf(v1.x); pk.s[3] = f2bf(v1.y);
        pk.s[4] = f2bf(v2.x); pk.s[5] = f2bf(v2.y);
        pk.s[6] = f2bf(v3.x); pk.s[7] = f2bf(v3.y);
      } else {
        #pragma unroll
        for (int e = 0; e < 8; ++e)
          pk.s[e] = (kbase + e < DIN) ? f2bf(src[e]) : (short)0;
      }
      *(int4*)&lA[ft * 512 + ul * 8] = pk.v;
    }
    // ---- stage B: 13 frag-tiles x 64 = 832 units ----
    #pragma unroll
    for (int r = 0; r < 4; ++r) {
      int u = t + 256 * r;
      if (u < 832) {
        int ft = u >> 6, ul = u & 63;
        int n = ft * 16 + (ul & 15);
        int kq = ul >> 4;
        int kbase = k0 + kq * 8;
        const float* src = nullptr;
        if (n < 100) src = Wf + (size_t)n * DIN + kbase;
        else if (n < 200) src = Wb + (size_t)(n - 100) * DIN + kbase;
        union { short s[8]; int4 v; } pk;
        if (src && kbase + 7 < DIN) {
          float2 v0 = *(const float2*)(src);
          float2 v1 = *(const float2*)(src + 2);
          float2 v2 = *(const float2*)(src + 4);
          float2 v3 = *(const float2*)(src + 6);
          pk.s[0] = f2bf(v0.x); pk.s[1] = f2bf(v0.y);
          pk.s[2] = f2bf(v1.x); pk.s[3] = f2bf(v1.y);
          pk.s[4] = f2bf(v2.x); pk.s[5] = f2bf(v2.y);
          pk.s[6] = f2bf(v3.x); pk.s[7] = f2bf(v3.y);
        } else {
          #pragma unroll
          for (int e = 0; e < 8; ++e)
            pk.s[e] = (src && kbase + e < DIN) ? f2bf(src[e]) : (short)0;
        }
        *(int4*)&lB[ft * 512 + ul * 8] = pk.v;
      }
    }
    __syncthreads();
    // ---- compute: 2 m-frags x 13 n-frags per wave ----
    short8 a0 = *(const short8*)&lA[(2 * wv + 0) * 512 + lane * 8];
    short8 a1 = *(const short8*)&lA[(2 * wv + 1) * 512 + lane * 8];
    #pragma unroll
    for (int nf = 0; nf < 13; ++nf) {
      short8 b = *(const short8*)&lB[nf * 512 + lane * 8];
      acc[0][nf] = __builtin_amdgcn_mfma_f32_16x16x32_bf16(a0, b, acc[0][nf], 0, 0, 0);
      acc[1][nf] = __builtin_amdgcn_mfma_f32_16x16x32_bf16(a1, b, acc[1][nf], 0, 0, 0);
    }
  }
  // ---- epilogue: C/D layout col=lane&15, row=(lane>>4)*4+reg [m89] ----
  const int r0 = (lane >> 4) * 4;
  #pragma unroll
  for (int mf = 0; mf < 2; ++mf) {
    #pragma unroll
    for (int nf = 0; nf < 13; ++nf) {
      int col = nf * 16 + li;
      if (col < 200) {
        float bv = lbias[col];
        int rowb = m0 + (2 * wv + mf) * 16 + r0;
        #pragma unroll
        for (int r = 0; r < 4; ++r)
          xp[(size_t)(rowb + r) * 200 + col] = acc[mf][nf][r] + bv;
      }
    }
  }
}

// ---------------------------------------------------------------------------
// K2: RNN scan, one (batch, dir) chain per workgroup. 320 threads:
//  t in [0,200): recurrence, 2 threads/output (k-split 52/48, padded to 52)
//  t in [256,294): tag-logit partials of previous step's h (wave 4)
// h ping-pong in LDS; xp prefetched 2 steps ahead; partial logits to plog.
// ---------------------------------------------------------------------------
__global__ __launch_bounds__(320) void k_rnn(
    const float* __restrict__ xp, const float* __restrict__ Whf, const float* __restrict__ Whb,
    const float* __restrict__ Wtag, float* __restrict__ plogf, float* __restrict__ plogb) {
  const int b = blockIdx.x;
  const int dir = blockIdx.y;
  const float* Whh = dir ? Whb : Whf;
  float* plog = dir ? plogb : plogf;
  __shared__ float hbuf[2][104];
  const int t = threadIdx.x;
  const bool isrec = (t < 200);
  const bool islog = (t >= 256 && t < 256 + 2 * TT);
  const int half = t & 1;
  const int kbase = half * 52;
  const int j = t >> 1;
  const int tg = (t - 256) >> 1;
  float4 Wreg[13];
  if (isrec) {
    #pragma unroll
    for (int q = 0; q < 13; ++q) {
      float tmp[4];
      #pragma unroll
      for (int e = 0; e < 4; ++e) {
        int k = kbase + 4 * q + e;
        tmp[e] = (k < HH) ? Whh[j * HH + k] : 0.f;
      }
      Wreg[q] = make_float4(tmp[0], tmp[1], tmp[2], tmp[3]);
    }
  } else if (islog) {
    #pragma unroll
    for (int q = 0; q < 13; ++q) {
      float tmp[4];
      #pragma unroll
      for (int e = 0; e < 4; ++e) {
        int k = kbase + 4 * q + e;
        tmp[e] = (k < HH) ? Wtag[tg * (2 * HH) + dir * HH + k] : 0.f;
      }
      Wreg[q] = make_float4(tmp[0], tmp[1], tmp[2], tmp[3]);
    }
  } else {
    #pragma unroll
    for (int q = 0; q < 13; ++q) Wreg[q] = make_float4(0.f, 0.f, 0.f, 0.f);
  }
  if (t < 104) { hbuf[0][t] = 0.f; hbuf[1][t] = 0.f; }
  __syncthreads();

  const int colbase = dir * HH;
  float xv0 = 0.f, xv1 = 0.f;
  if (isrec && half == 0) {
    int sx0 = dir ? (SS - 1) : 0;
    int sx1 = dir ? (SS - 2) : 1;
    xv0 = xp[((size_t)sx0 * BB + b) * 200 + colbase + j];
    xv1 = xp[((size_t)sx1 * BB + b) * 200 + colbase + j];
  }
  int p = 0;
  for (int s = 0; s < SS; ++s) {
    float xv2 = 0.f;
    if (isrec && half == 0 && s + 2 < SS) {
      int sx2 = dir ? (SS - 3 - s) : (s + 2);
      xv2 = xp[((size_t)sx2 * BB + b) * 200 + colbase + j];
    }
    float acc = 0.f;
    const bool work = isrec || (islog && s > 0);
    if (work) {
      const float* hp = hbuf[p];
      #pragma unroll
      for (int q = 0; q < 13; ++q) {
        float4 h4 = *(const float4*)&hp[kbase + 4 * q];
        acc = fmaf(Wreg[q].x, h4.x, acc);
        acc = fmaf(Wreg[q].y, h4.y, acc);
        acc = fmaf(Wreg[q].z, h4.z, acc);
        acc = fmaf(Wreg[q].w, h4.w, acc);
      }
      acc += __shfl_xor(acc, 1);
    }
    float hnew = 0.f;
    if (isrec && half == 0) {
      float z = xv0 + acc;
      float e = __expf(-2.f * fabsf(z));
      float th = __fdividef(1.f - e, 1.f + e);
      hnew = copysignf(th, z);
    }
    if (islog && s > 0 && half == 0) {
      int sxp = dir ? (SS - s) : (s - 1);  // seq index of h_{s-1}
      plog[((size_t)sxp * BB + b) * TT + tg] = acc;
    }
    if (isrec && half == 0) hbuf[1 - p][j] = hnew;
    __syncthreads();
    p ^= 1;
    xv0 = xv1; xv1 = xv2;
  }
  // logits of the final h (in hbuf[p])
  if (islog) {
    float acc = 0.f;
    const float* hp = hbuf[p];
    #pragma unroll
    for (int q = 0; q < 13; ++q) {
      float4 h4 = *(const float4*)&hp[kbase + 4 * q];
      acc = fmaf(Wreg[q].x, h4.x, acc);
      acc = fmaf(Wreg[q].y, h4.y, acc);
      acc = fmaf(Wreg[q].z, h4.z, acc);
      acc = fmaf(Wreg[q].w, h4.w, acc);
    }
    acc += __shfl_xor(acc, 1);
    if (half == 0) {
      int sxp = dir ? 0 : (SS - 1);
      plog[((size_t)sxp * BB + b) * TT + tg] = acc;
    }
  }
}

// ---------------------------------------------------------------------------
// K3: logits = plogf + plogb + b_tag; probs = softmax over 19 tags.
// ---------------------------------------------------------------------------
__global__ __launch_bounds__(256) void k_softmax(
    const float* __restrict__ plogf, const float* __restrict__ plogb,
    const float* __restrict__ btag, float* __restrict__ probs) {
  __shared__ float ls[BB * TT];  // 4864 floats
  const size_t base = (size_t)blockIdx.x * (BB * TT);
  const int t = threadIdx.x;
  #pragma unroll
  for (int i = 0; i < TT; ++i) {
    int idx = t + 256 * i;
    ls[idx] = plogf[base + idx] + plogb[base + idx] + btag[idx % TT];
  }
  __syncthreads();
  float v[TT];
  float m = -1e30f;
  #pragma unroll
  for (int i = 0; i < TT; ++i) { v[i] = ls[t * TT + i]; m = fmaxf(m, v[i]); }
  float ssum = 0.f;
  #pragma unroll
  for (int i = 0; i < TT; ++i) { v[i] = __expf(v[i] - m); ssum += v[i]; }
  float inv = __fdividef(1.f, ssum);
  #pragma unroll
  for (int i = 0; i < TT; ++i) ls[t * TT + i] = v[i] * inv;
  __syncthreads();
  #pragma unroll
  for (int i = 0; i < TT; ++i) {
    int idx = t + 256 * i;
    probs[base + idx] = ls[idx];
  }
}

// ---------------------------------------------------------------------------
// K4: CRF sum log-likelihood. One wave per sequence (n = s index, L = BB).
// ---------------------------------------------------------------------------
__global__ __launch_bounds__(256) void k_crf(
    const float* __restrict__ probs, const int* __restrict__ y,
    const float* __restrict__ start, const float* __restrict__ endt,
    const float* __restrict__ trans, float* __restrict__ out) {
  __shared__ float ltr[TT * TT];
  __shared__ float lem[4][64 * TT];
  const int t = threadIdx.x;
  const int wave = t >> 6, lane = t & 63;
  const int n = blockIdx.x * 4 + wave;
  for (int i = t; i < TT * TT; i += 256) ltr[i] = trans[i];
  __syncthreads();
  const float* em = probs + (size_t)n * BB * TT;
  const int* yn = y + n * BB;
  float Ereg[TT];
  #pragma unroll
  for (int i = 0; i < TT; ++i) Ereg[i] = (lane < TT) ? __expf(ltr[i * TT + lane]) : 0.f;
  float num = 0.f;
  float alpha = -1e30f;
  for (int c = 0; c < 4; ++c) {
    __syncthreads();
    for (int i = lane; i < 64 * TT; i += 64) lem[wave][i] = em[c * (64 * TT) + i];
    __syncthreads();
    {  // numerator piece: l = c*64 + lane
      int l = c * 64 + lane;
      int yt = yn[l];
      num += lem[wave][lane * TT + yt];
      if (l < BB - 1) num += ltr[yt * TT + yn[l + 1]];
    }
    int llstart = 0;
    if (c == 0) {
      alpha = (lane < TT) ? (start[lane] + lem[wave][lane]) : -1e30f;
      llstart = 1;
    }
    for (int ll = llstart; ll < 64; ++ll) {
      float m = rfl(alpha);
      float ea = __expf(alpha - m);
      float s0 = 0.f, s1 = 0.f;
      #pragma unroll
      for (int i = 0; i < TT; i += 2) {
        s0 = fmaf(rl(ea, i), Ereg[i], s0);
        if (i + 1 < TT) s1 = fmaf(rl(ea, i + 1), Ereg[i + 1], s1);
      }
      float ssum = s0 + s1;
      float em_l = (lane < TT) ? lem[wave][ll * TT + lane] : 0.f;
      alpha = em_l + m + __logf(ssum);
    }
  }
  #pragma unroll
  for (int o = 1; o < 64; o <<= 1) num += __shfl_xor(num, o);
  float av = alpha + ((lane < TT) ? endt[lane] : 0.f);
  float m2 = rfl(av);
  float ex = (lane < TT) ? __expf(av - m2) : 0.f;
  #pragma unroll
  for (int o = 1; o < 64; o <<= 1) ex += __shfl_xor(ex, o);
  if (lane == 0) {
    float denom = m2 + __logf(ex);
    float res = (start[yn[0]] + endt[yn[BB - 1]] + num) - denom;
    atomicAdd(out, res);
  }
}

// ---------------------------------------------------------------------------
extern "C" void kernel_launch(void* const* d_in, const int* in_sizes, int n_in,
                              void* d_out, int out_size, void* d_ws, size_t ws_size,
                              hipStream_t stream) {
  const float* x     = (const float*)d_in[0];
  const int*   y     = (const int*)d_in[1];
  const float* Wihf  = (const float*)d_in[2];
  const float* Whhf  = (const float*)d_in[3];
  const float* bihf  = (const float*)d_in[4];
  const float* bhhf  = (const float*)d_in[5];
  const float* Wihb  = (const float*)d_in[6];
  const float* Whhb  = (const float*)d_in[7];
  const float* bihb  = (const float*)d_in[8];
  const float* bhhb  = (const float*)d_in[9];
  const float* Wtag  = (const float*)d_in[10];
  const float* btag  = (const float*)d_in[11];
  const float* stt   = (const float*)d_in[12];
  const float* endt  = (const float*)d_in[13];
  const float* trans = (const float*)d_in[14];

  float* ws    = (float*)d_ws;
  float* xp    = ws;                                    // 131072*200 floats
  float* plogf = xp    + (size_t)131072 * 200;          // 131072*19
  float* plogb = plogf + (size_t)131072 * TT;           // 131072*19
  float* probs = plogb + (size_t)131072 * TT;           // 131072*19

  hipMemsetAsync(d_out, 0, sizeof(float) * out_size, stream);

  k_inproj<<<dim3(1024), 256, 0, stream>>>(x, Wihf, Wihb, bihf, bhhf, bihb, bhhb, xp);
  k_rnn<<<dim3(256, 2), 320, 0, stream>>>(xp, Whhf, Whhb, Wtag, plogf, plogb);
  k_softmax<<<512, 256, 0, stream>>>(plogf, plogb, btag, probs);
  k_crf<<<128, 256, 0, stream>>>(probs, y, stt, endt, trans, (float*)d_out);
}

// Round 3
// 541.331 us; speedup vs baseline: 1.5362x; 1.0591x over previous
//
#include <hip/hip_runtime.h>
#include <math.h>

#define SS 512
#define BB 256
#define DIN 202
#define HH 100
#define TT 19

typedef short short8 __attribute__((ext_vector_type(8)));
typedef float f32x4 __attribute__((ext_vector_type(4)));

__device__ __forceinline__ float rl(float v, int i) {
    return __int_as_float(__builtin_amdgcn_readlane(__float_as_int(v), i));
}
__device__ __forceinline__ float rfl(float v) {
    return __int_as_float(__builtin_amdgcn_readfirstlane(__float_as_int(v)));
}
__device__ __forceinline__ short f2bf(float f) {
  unsigned u = __float_as_uint(f);
  u += 0x7fff + ((u >> 16) & 1);   // RNE; inputs are well-behaved (no NaN/Inf)
  return (short)(u >> 16);
}
__device__ __forceinline__ float fast_tanh(float z) {
  float e = __expf(-2.f * fabsf(z));
  float th = __fdividef(1.f - e, 1.f + e);
  return copysignf(th, z);
}

// ---------------------------------------------------------------------------
// K1: input projection via bf16 MFMA (unchanged from R2 — passed).
// ---------------------------------------------------------------------------
__global__ __launch_bounds__(256) void k_inproj(
    const float* __restrict__ x,
    const float* __restrict__ Wf, const float* __restrict__ Wb,
    const float* __restrict__ bihf, const float* __restrict__ bhhf,
    const float* __restrict__ bihb, const float* __restrict__ bhhb,
    float* __restrict__ xp) {
  __shared__ short lA[8 * 512];
  __shared__ short lB[13 * 512];
  __shared__ float lbias[208];
  const int t = threadIdx.x;
  const int m0 = blockIdx.x * 128;
  const int wv = t >> 6, lane = t & 63;
  const int li = lane & 15;

  if (t < 208) {
    float bv = 0.f;
    if (t < 100) bv = bihf[t] + bhhf[t];
    else if (t < 200) bv = bihb[t - 100] + bhhb[t - 100];
    lbias[t] = bv;
  }

  f32x4 acc[2][13];
  #pragma unroll
  for (int mf = 0; mf < 2; ++mf)
    #pragma unroll
    for (int nf = 0; nf < 13; ++nf)
      acc[mf][nf] = (f32x4){0.f, 0.f, 0.f, 0.f};

  for (int kc = 0; kc < 7; ++kc) {
    const int k0 = kc * 32;
    __syncthreads();
    #pragma unroll
    for (int r = 0; r < 2; ++r) {
      int u = t + 256 * r;
      int ft = u >> 6, ul = u & 63;
      int i = ul & 15, kq = ul >> 4;
      int kbase = k0 + kq * 8;
      const float* src = x + (size_t)(m0 + ft * 16 + i) * DIN + kbase;
      union { short s[8]; int4 v; } pk;
      if (kbase + 7 < DIN) {
        float2 v0 = *(const float2*)(src);
        float2 v1 = *(const float2*)(src + 2);
        float2 v2 = *(const float2*)(src + 4);
        float2 v3 = *(const float2*)(src + 6);
        pk.s[0] = f2bf(v0.x); pk.s[1] = f2bf(v0.y);
        pk.s[2] = f2bf(v1.x); pk.s[3] = f2bf(v1.y);
        pk.s[4] = f2bf(v2.x); pk.s[5] = f2bf(v2.y);
        pk.s[6] = f2bf(v3.x); pk.s[7] = f2bf(v3.y);
      } else {
        #pragma unroll
        for (int e = 0; e < 8; ++e)
          pk.s[e] = (kbase + e < DIN) ? f2bf(src[e]) : (short)0;
      }
      *(int4*)&lA[ft * 512 + ul * 8] = pk.v;
    }
    #pragma unroll
    for (int r = 0; r < 4; ++r) {
      int u = t + 256 * r;
      if (u < 832) {
        int ft = u >> 6, ul = u & 63;
        int n = ft * 16 + (ul & 15);
        int kq = ul >> 4;
        int kbase = k0 + kq * 8;
        const float* src = nullptr;
        if (n < 100) src = Wf + (size_t)n * DIN + kbase;
        else if (n < 200) src = Wb + (size_t)(n - 100) * DIN + kbase;
        union { short s[8]; int4 v; } pk;
        if (src && kbase + 7 < DIN) {
          float2 v0 = *(const float2*)(src);
          float2 v1 = *(const float2*)(src + 2);
          float2 v2 = *(const float2*)(src + 4);
          float2 v3 = *(const float2*)(src + 6);
          pk.s[0] = f2bf(v0.x); pk.s[1] = f2bf(v0.y);
          pk.s[2] = f2bf(v1.x); pk.s[3] = f2bf(v1.y);
          pk.s[4] = f2bf(v2.x); pk.s[5] = f2bf(v2.y);
          pk.s[6] = f2bf(v3.x); pk.s[7] = f2bf(v3.y);
        } else {
          #pragma unroll
          for (int e = 0; e < 8; ++e)
            pk.s[e] = (src && kbase + e < DIN) ? f2bf(src[e]) : (short)0;
        }
        *(int4*)&lB[ft * 512 + ul * 8] = pk.v;
      }
    }
    __syncthreads();
    short8 a0 = *(const short8*)&lA[(2 * wv + 0) * 512 + lane * 8];
    short8 a1 = *(const short8*)&lA[(2 * wv + 1) * 512 + lane * 8];
    #pragma unroll
    for (int nf = 0; nf < 13; ++nf) {
      short8 b = *(const short8*)&lB[nf * 512 + lane * 8];
      acc[0][nf] = __builtin_amdgcn_mfma_f32_16x16x32_bf16(a0, b, acc[0][nf], 0, 0, 0);
      acc[1][nf] = __builtin_amdgcn_mfma_f32_16x16x32_bf16(a1, b, acc[1][nf], 0, 0, 0);
    }
  }
  const int r0 = (lane >> 4) * 4;
  #pragma unroll
  for (int mf = 0; mf < 2; ++mf) {
    #pragma unroll
    for (int nf = 0; nf < 13; ++nf) {
      int col = nf * 16 + li;
      if (col < 200) {
        float bv = lbias[col];
        int rowb = m0 + (2 * wv + mf) * 16 + r0;
        #pragma unroll
        for (int r = 0; r < 4; ++r)
          xp[(size_t)(rowb + r) * 200 + col] = acc[mf][nf][r] + bv;
      }
    }
  }
}

// ---------------------------------------------------------------------------
// K2 (REWRITTEN): MFMA RNN scan. Block = 16 batch chains x 1 dir, 9 waves.
//   waves 0-6: m-frag w (h rows 16w..16w+15): acc = mfma(Whh_frags, h_frags,
//              C=xp_frag); tanh 4 vals/lane; pack bf16; 1 ds_write_b64 into
//              next step's B-linear buffer; 1 barrier/step.
//   waves 7-8: tag-logit partials of h_{s-1} (Wtag frags in VGPRs), scalar
//              stores to plog.
// A-frag (Whh/Wtag) layout: lane holds A[m=lane&15][k=32q+8*(lane>>4)+j],
// zero-padded past row/col 100. B buffer: chunk q, lane l owns 16B at
// q*1024 + l*16 (B[k=32q+8p+j][n=lane&15], h as bf16).
// ---------------------------------------------------------------------------
__global__ __launch_bounds__(576) void k_rnn(
    const float* __restrict__ xp, const float* __restrict__ Whf, const float* __restrict__ Whb,
    const float* __restrict__ Wtag, float* __restrict__ plogf, float* __restrict__ plogb) {
  const int g = blockIdx.x;
  const int dir = g & 1;
  const int b0 = (g >> 1) * 16;
  const float* Whh = dir ? Whb : Whf;
  float* plog = dir ? plogb : plogf;

  __shared__ short hb[2][4 * 512];  // 2 buffers x 4 k-chunks x 512 bf16

  const int t = threadIdx.x;
  const int wv = t >> 6, lane = t & 63;
  const int n = lane & 15, p = lane >> 4;
  const bool isrec = (wv < 7);

  // zero both h buffers (h_{-1} = 0)
  for (int i = t; i < 2048; i += 576) ((unsigned*)hb)[i] = 0u;

  // ---- one-time A-fragment load into VGPRs ----
  short8 af[4];
  #pragma unroll
  for (int q = 0; q < 4; ++q) af[q] = (short8){0, 0, 0, 0, 0, 0, 0, 0};
  {
    const float* rowp = nullptr;
    if (isrec) {
      int arow = 16 * wv + n;
      if (arow < HH) rowp = Whh + (size_t)arow * HH;
    } else {
      int tag = 16 * (wv - 7) + n;
      if (tag < TT) rowp = Wtag + (size_t)tag * (2 * HH) + dir * HH;
    }
    if (rowp) {
      #pragma unroll
      for (int q = 0; q < 3; ++q) {
        float4 v0 = *(const float4*)(rowp + 32 * q + 8 * p);
        float4 v1 = *(const float4*)(rowp + 32 * q + 8 * p + 4);
        af[q] = (short8){f2bf(v0.x), f2bf(v0.y), f2bf(v0.z), f2bf(v0.w),
                         f2bf(v1.x), f2bf(v1.y), f2bf(v1.z), f2bf(v1.w)};
      }
      if (p == 0) {  // chunk 3: k = 96..103, only 96..99 valid
        float4 v0 = *(const float4*)(rowp + 96);
        af[3] = (short8){f2bf(v0.x), f2bf(v0.y), f2bf(v0.z), f2bf(v0.w), 0, 0, 0, 0};
      }
    }
  }

  // ---- xp prefetch pipeline (rec waves, valid rows only) ----
  const bool xvalid = isrec && ((wv < 6) || (p == 0));
  const int row = 16 * wv + 4 * p;  // h-row base this lane produces
  const float* xptr = nullptr;
  ptrdiff_t xstep = 0;
  float4 fx0 = {0, 0, 0, 0}, fx1 = {0, 0, 0, 0}, fx2 = {0, 0, 0, 0};
  if (xvalid) {
    int s0 = dir ? (SS - 1) : 0;
    xptr = xp + (size_t)(s0 * BB + b0 + n) * 200 + dir * HH + row;
    xstep = dir ? -(ptrdiff_t)(BB * 200) : (ptrdiff_t)(BB * 200);
    fx0 = *(const float4*)(xptr);
    fx1 = *(const float4*)(xptr + xstep);
    xptr += 2 * xstep;
  }
  // B-write target for rec waves
  const int wq = wv >> 1;
  const int widx = wq * 512 + (n + 16 * (2 * (wv & 1) + (p >> 1))) * 8 + (p & 1) * 4;

  __syncthreads();

  int pp = 0;
  for (int s = 0; s < SS; ++s) {
    if (isrec) {
      if (xvalid && s + 2 < SS) { fx2 = *(const float4*)(xptr); xptr += xstep; }
      f32x4 acc = {fx0.x, fx0.y, fx0.z, fx0.w};
      #pragma unroll
      for (int q = 0; q < 4; ++q) {
        short8 b = *(const short8*)&hb[pp][q * 512 + lane * 8];
        acc = __builtin_amdgcn_mfma_f32_16x16x32_bf16(af[q], b, acc, 0, 0, 0);
      }
      float h0 = fast_tanh(acc[0]);
      float h1 = fast_tanh(acc[1]);
      float h2 = fast_tanh(acc[2]);
      float h3 = fast_tanh(acc[3]);
      unsigned lo = ((unsigned)(unsigned short)f2bf(h1) << 16) | (unsigned short)f2bf(h0);
      unsigned hi = ((unsigned)(unsigned short)f2bf(h3) << 16) | (unsigned short)f2bf(h2);
      uint2 wval; wval.x = lo; wval.y = hi;
      *(uint2*)&hb[1 - pp][widx] = wval;
      fx0 = fx1; fx1 = fx2;
    } else if (s > 0) {
      f32x4 acc = {0.f, 0.f, 0.f, 0.f};
      #pragma unroll
      for (int q = 0; q < 4; ++q) {
        short8 b = *(const short8*)&hb[pp][q * 512 + lane * 8];
        acc = __builtin_amdgcn_mfma_f32_16x16x32_bf16(af[q], b, acc, 0, 0, 0);
      }
      int sp = dir ? (SS - s) : (s - 1);
      float* dst = plog + (size_t)(sp * BB + b0 + n) * TT;
      if (wv == 7) {
        dst += 4 * p;
        dst[0] = acc[0]; dst[1] = acc[1]; dst[2] = acc[2]; dst[3] = acc[3];
      } else if (p == 0) {
        dst[16] = acc[0]; dst[17] = acc[1]; dst[18] = acc[2];
      }
    }
    __syncthreads();
    pp ^= 1;
  }
  // final logit round: h_{511} is in hb[pp]
  if (!isrec) {
    f32x4 acc = {0.f, 0.f, 0.f, 0.f};
    #pragma unroll
    for (int q = 0; q < 4; ++q) {
      short8 b = *(const short8*)&hb[pp][q * 512 + lane * 8];
      acc = __builtin_amdgcn_mfma_f32_16x16x32_bf16(af[q], b, acc, 0, 0, 0);
    }
    int sp = dir ? 0 : (SS - 1);
    float* dst = plog + (size_t)(sp * BB + b0 + n) * TT;
    if (wv == 7) {
      dst += 4 * p;
      dst[0] = acc[0]; dst[1] = acc[1]; dst[2] = acc[2]; dst[3] = acc[3];
    } else if (p == 0) {
      dst[16] = acc[0]; dst[17] = acc[1]; dst[18] = acc[2];
    }
  }
}

// ---------------------------------------------------------------------------
// K3: logits = plogf + plogb + b_tag; probs = softmax over 19 tags.
// ---------------------------------------------------------------------------
__global__ __launch_bounds__(256) void k_softmax(
    const float* __restrict__ plogf, const float* __restrict__ plogb,
    const float* __restrict__ btag, float* __restrict__ probs) {
  __shared__ float ls[BB * TT];
  const size_t base = (size_t)blockIdx.x * (BB * TT);
  const int t = threadIdx.x;
  #pragma unroll
  for (int i = 0; i < TT; ++i) {
    int idx = t + 256 * i;
    ls[idx] = plogf[base + idx] + plogb[base + idx] + btag[idx % TT];
  }
  __syncthreads();
  float v[TT];
  float m = -1e30f;
  #pragma unroll
  for (int i = 0; i < TT; ++i) { v[i] = ls[t * TT + i]; m = fmaxf(m, v[i]); }
  float ssum = 0.f;
  #pragma unroll
  for (int i = 0; i < TT; ++i) { v[i] = __expf(v[i] - m); ssum += v[i]; }
  float inv = __fdividef(1.f, ssum);
  #pragma unroll
  for (int i = 0; i < TT; ++i) ls[t * TT + i] = v[i] * inv;
  __syncthreads();
  #pragma unroll
  for (int i = 0; i < TT; ++i) {
    int idx = t + 256 * i;
    probs[base + idx] = ls[idx];
  }
}

// ---------------------------------------------------------------------------
// K4: CRF sum log-likelihood. One wave per sequence (n = s index, L = BB).
// ---------------------------------------------------------------------------
__global__ __launch_bounds__(256) void k_crf(
    const float* __restrict__ probs, const int* __restrict__ y,
    const float* __restrict__ start, const float* __restrict__ endt,
    const float* __restrict__ trans, float* __restrict__ out) {
  __shared__ float ltr[TT * TT];
  __shared__ float lem[4][64 * TT];
  const int t = threadIdx.x;
  const int wave = t >> 6, lane = t & 63;
  const int n = blockIdx.x * 4 + wave;
  for (int i = t; i < TT * TT; i += 256) ltr[i] = trans[i];
  __syncthreads();
  const float* em = probs + (size_t)n * BB * TT;
  const int* yn = y + n * BB;
  float Ereg[TT];
  #pragma unroll
  for (int i = 0; i < TT; ++i) Ereg[i] = (lane < TT) ? __expf(ltr[i * TT + lane]) : 0.f;
  float num = 0.f;
  float alpha = -1e30f;
  for (int c = 0; c < 4; ++c) {
    __syncthreads();
    for (int i = lane; i < 64 * TT; i += 64) lem[wave][i] = em[c * (64 * TT) + i];
    __syncthreads();
    {
      int l = c * 64 + lane;
      int yt = yn[l];
      num += lem[wave][lane * TT + yt];
      if (l < BB - 1) num += ltr[yt * TT + yn[l + 1]];
    }
    int llstart = 0;
    if (c == 0) {
      alpha = (lane < TT) ? (start[lane] + lem[wave][lane]) : -1e30f;
      llstart = 1;
    }
    for (int ll = llstart; ll < 64; ++ll) {
      float m = rfl(alpha);
      float ea = __expf(alpha - m);
      float s0 = 0.f, s1 = 0.f;
      #pragma unroll
      for (int i = 0; i < TT; i += 2) {
        s0 = fmaf(rl(ea, i), Ereg[i], s0);
        if (i + 1 < TT) s1 = fmaf(rl(ea, i + 1), Ereg[i + 1], s1);
      }
      float ssum = s0 + s1;
      float em_l = (lane < TT) ? lem[wave][ll * TT + lane] : 0.f;
      alpha = em_l + m + __logf(ssum);
    }
  }
  #pragma unroll
  for (int o = 1; o < 64; o <<= 1) num += __shfl_xor(num, o);
  float av = alpha + ((lane < TT) ? endt[lane] : 0.f);
  float m2 = rfl(av);
  float ex = (lane < TT) ? __expf(av - m2) : 0.f;
  #pragma unroll
  for (int o = 1; o < 64; o <<= 1) ex += __shfl_xor(ex, o);
  if (lane == 0) {
    float denom = m2 + __logf(ex);
    float res = (start[yn[0]] + endt[yn[BB - 1]] + num) - denom;
    atomicAdd(out, res);
  }
}

// ---------------------------------------------------------------------------
extern "C" void kernel_launch(void* const* d_in, const int* in_sizes, int n_in,
                              void* d_out, int out_size, void* d_ws, size_t ws_size,
                              hipStream_t stream) {
  const float* x     = (const float*)d_in[0];
  const int*   y     = (const int*)d_in[1];
  const float* Wihf  = (const float*)d_in[2];
  const float* Whhf  = (const float*)d_in[3];
  const float* bihf  = (const float*)d_in[4];
  const float* bhhf  = (const float*)d_in[5];
  const float* Wihb  = (const float*)d_in[6];
  const float* Whhb  = (const float*)d_in[7];
  const float* bihb  = (const float*)d_in[8];
  const float* bhhb  = (const float*)d_in[9];
  const float* Wtag  = (const float*)d_in[10];
  const float* btag  = (const float*)d_in[11];
  const float* stt   = (const float*)d_in[12];
  const float* endt  = (const float*)d_in[13];
  const float* trans = (const float*)d_in[14];

  float* ws    = (float*)d_ws;
  float* xp    = ws;                                    // 131072*200 floats
  float* plogf = xp    + (size_t)131072 * 200;          // 131072*19
  float* plogb = plogf + (size_t)131072 * TT;           // 131072*19
  float* probs = plogb + (size_t)131072 * TT;           // 131072*19

  hipMemsetAsync(d_out, 0, sizeof(float) * out_size, stream);

  k_inproj<<<dim3(1024), 256, 0, stream>>>(x, Wihf, Wihb, bihf, bhhf, bihb, bhhb, xp);
  k_rnn<<<dim3(32), 576, 0, stream>>>(xp, Whhf, Whhb, Wtag, plogf, plogb);
  k_softmax<<<512, 256, 0, stream>>>(plogf, plogb, btag, probs);
  k_crf<<<128, 256, 0, stream>>>(probs, y, stt, endt, trans, (float*)d_out);
}